// Round 2
// baseline (1017.389 us; speedup 1.0000x reference)
//
#include <hip/hip_runtime.h>
#include <hip/hip_bf16.h>
#include <stdint.h>

#define SEQ 2048
#define EMB 1024

typedef __attribute__((ext_vector_type(4))) float f32x4;
typedef __attribute__((ext_vector_type(8))) __bf16 bf16x8v;
typedef __attribute__((ext_vector_type(8))) unsigned short u16x8;
typedef __attribute__((ext_vector_type(4))) unsigned short u16x4;

static __device__ __forceinline__ float bf2f(unsigned short u){
  union { unsigned int i; float f; } v; v.i = ((unsigned int)u) << 16; return v.f;
}
static __device__ __forceinline__ unsigned short f2bf(float f){
  union { float f; unsigned int i; } v; v.f = f;
  unsigned int r = v.i + 0x7FFFu + ((v.i >> 16) & 1u);
  return (unsigned short)(r >> 16);
}

static __device__ __forceinline__ void gload16(const unsigned short* g, unsigned short* l){
  __builtin_amdgcn_global_load_lds(
      (__attribute__((address_space(1))) unsigned int*)(g),
      (__attribute__((address_space(3))) unsigned int*)(l), 16, 0, 0);
}

// ---------------- converters ----------------
__global__ __launch_bounds__(256) void k_cvt_bf16(const float* __restrict__ in,
                                                  unsigned short* __restrict__ out, long n4){
  long i = (long)blockIdx.x * 256 + threadIdx.x;
  if (i >= n4) return;
  float4 v = ((const float4*)in)[i];
  u16x4 o; o.x = f2bf(v.x); o.y = f2bf(v.y); o.z = f2bf(v.z); o.w = f2bf(v.w);
  ((u16x4*)out)[i] = o;
}

__global__ __launch_bounds__(256) void k_build_wcat(
    const float* __restrict__ w0, const float* __restrict__ w1,
    const float* __restrict__ w2, const float* __restrict__ w3,
    const float* __restrict__ w4, const float* __restrict__ w5,
    unsigned short* __restrict__ wcat){
  long i = (long)blockIdx.x * 256 + threadIdx.x;   // chunk of 4 elems
  long g = i * 4;                                   // total 12288*1024 elems
  int m = (int)(g >> 21);                           // 2048*1024 = 2^21 per matrix
  const float* src = (m==0)?w0:(m==1)?w1:(m==2)?w2:(m==3)?w3:(m==4)?w4:w5;
  long loc = g & ((1L<<21)-1);
  float4 v = *(const float4*)&src[loc];
  u16x4 o; o.x=f2bf(v.x); o.y=f2bf(v.y); o.z=f2bf(v.z); o.w=f2bf(v.w);
  *(u16x4*)&wcat[g] = o;
}

__global__ __launch_bounds__(256) void k_build_bcat(
    const float* b0, const float* b1, const float* b2,
    const float* b3, const float* b4, const float* b5, float* __restrict__ bcat){
  int i = blockIdx.x * 256 + threadIdx.x;  // 12288
  int m = i >> 11;
  const float* src = (m==0)?b0:(m==1)?b1:(m==2)?b2:(m==3)?b3:(m==4)?b4:b5;
  bcat[i] = src[i & 2047];
}

// ---------------- GEMM (C = A @ B^T, row-major A[M,K], B[N,K]) ----------------
// m97-style: 128x128 tile, BK=64, 256 threads (4 waves 2x2), mfma 16x16x32 bf16
#define M_LIN   0
#define M_SCORE 1
#define M_PV    2
#define M_OUT   3

template<int MODE>
__global__ __launch_bounds__(256)
void gemm_bt(const unsigned short* __restrict__ A_,
             const unsigned short* __restrict__ B_,
             float* __restrict__ Cf, unsigned short* __restrict__ Cb,
             const float* __restrict__ bias, const float* __restrict__ tfb,
             int tilesN, int accflag)
{
  constexpr int LDA = (MODE==M_LIN)?1024:(MODE==M_SCORE)?6144:2048;
  constexpr int LDB = (MODE==M_LIN)?1024:(MODE==M_SCORE)?6144:2048;
  constexpr int KD  = (MODE==M_LIN||MODE==M_SCORE)?1024:2048;
  constexpr int LDC = (MODE==M_LIN)?6144:(MODE==M_SCORE)?2048:(MODE==M_PV)?2048:1024;

  __shared__ unsigned short As[128*64];
  __shared__ unsigned short Bs[128*64];

  const int tid  = threadIdx.x;
  const int tile = blockIdx.x;
  const int tm = tile / tilesN, tn = tile % tilesN;
  const int y = blockIdx.y;

  const unsigned short *A0 = A_, *B0 = B_;
  unsigned short* Cbp = Cb;
  float* Cfp = Cf;
  const float* trow = nullptr;

  if constexpr (MODE==M_SCORE) {
    int bl = y >> 1, d = y & 1;
    A0 = A_ + (size_t)bl*SEQ*6144 + d*1024;        // Q  (chunk-local batch bl)
    B0 = A0 + 2048;                                // K
    Cbp = Cb + (size_t)y*SEQ*SEQ;
    trow = tfb + (size_t)bl*SEQ;
  } else if constexpr (MODE==M_PV) {
    A0 = A_ + (size_t)y*SEQ*SEQ;                   // P head y
    B0 = B_ + (size_t)y*EMB*SEQ;                   // V^T head y
    Cbp = Cb + (size_t)(y>>1)*SEQ*2048 + (y&1)*1024;  // AO[bl][s][d*1024+e]
  }

  const int rbase = tid >> 3, cel = (tid & 7) * 8;
  const int wid = tid >> 6, lane = tid & 63;
  const int wr = wid >> 1, wc = wid & 1;
  const int lrow = lane & 15, lk = (lane >> 4) * 8;

  f32x4 acc[4][4];
  #pragma unroll
  for (int m=0;m<4;++m)
    #pragma unroll
    for (int n=0;n<4;++n)
      #pragma unroll
      for (int r=0;r<4;++r) acc[m][n][r] = 0.f;

  const unsigned short* gA = A0 + (size_t)(tm*128 + rbase)*LDA + cel;
  const unsigned short* gB = B0 + (size_t)(tn*128 + rbase)*LDB + cel;
  for (int k0 = 0; k0 < KD; k0 += 64) {
    #pragma unroll
    for (int it = 0; it < 4; ++it) {
      gload16(gA + (size_t)(it*32)*LDA + k0, &As[it*2048 + tid*8]);
      gload16(gB + (size_t)(it*32)*LDB + k0, &Bs[it*2048 + tid*8]);
    }
    __syncthreads();
    #pragma unroll
    for (int kk = 0; kk < 2; ++kk) {
      bf16x8v a[4], b[4];
      #pragma unroll
      for (int m=0;m<4;++m) a[m] = *(const bf16x8v*)&As[(wr*64+m*16+lrow)*64 + kk*32 + lk];
      #pragma unroll
      for (int n=0;n<4;++n) b[n] = *(const bf16x8v*)&Bs[(wc*64+n*16+lrow)*64 + kk*32 + lk];
      #pragma unroll
      for (int m=0;m<4;++m)
        #pragma unroll
        for (int n=0;n<4;++n)
          acc[m][n] = __builtin_amdgcn_mfma_f32_16x16x32_bf16(a[m], b[n], acc[m][n], 0, 0, 0);
    }
    __syncthreads();
  }

  // epilogue: C/D layout col = lane&15, row = (lane>>4)*4 + reg
  const int rr = (lane >> 4) * 4, cc = lane & 15;
  const int row0 = tm*128 + wr*64, col0 = tn*128 + wc*64;
  #pragma unroll
  for (int n=0;n<4;++n) {
    int col = col0 + n*16 + cc;
    float cmul = 1.f, cadd = 0.f;
    if constexpr (MODE==M_SCORE) cmul = 0.03125f * trow[col];
    if constexpr (MODE==M_LIN)   cadd = bias[col];
    #pragma unroll
    for (int m=0;m<4;++m) {
      #pragma unroll
      for (int r=0;r<4;++r) {
        int row = row0 + m*16 + rr + r;
        float v = acc[m][n][r];
        if constexpr (MODE==M_SCORE) v *= cmul;
        if constexpr (MODE==M_LIN)   v += cadd;
        if constexpr (MODE==M_OUT) {
          size_t idx = (size_t)row*LDC + col;
          float w = v + (accflag ? Cfp[idx] : bias[col]);
          Cfp[idx] = w;
        } else {
          Cbp[(size_t)row*LDC + col] = f2bf(v);
        }
      }
    }
  }
}

// ---------------- row softmax (in-place, bf16) ----------------
__global__ __launch_bounds__(256) void k_softmax(unsigned short* __restrict__ Sc){
  long row = blockIdx.x;
  unsigned short* p = Sc + row*SEQ + threadIdx.x*8;
  u16x8 raw = *(const u16x8*)p;
  float v[8]; float mx = -3.0e38f;
  #pragma unroll
  for (int j=0;j<8;++j){ v[j] = bf2f(raw[j]); mx = fmaxf(mx, v[j]); }
  #pragma unroll
  for (int o=1;o<64;o<<=1) mx = fmaxf(mx, __shfl_xor(mx, o));
  __shared__ float redm[4], reds[4];
  int wid = threadIdx.x >> 6, lane = threadIdx.x & 63;
  if (lane == 0) redm[wid] = mx;
  __syncthreads();
  mx = fmaxf(fmaxf(redm[0],redm[1]), fmaxf(redm[2],redm[3]));
  float s = 0.f;
  #pragma unroll
  for (int j=0;j<8;++j){ v[j] = __expf(v[j]-mx); s += v[j]; }
  #pragma unroll
  for (int o=1;o<64;o<<=1) s += __shfl_xor(s, o);
  if (lane == 0) reds[wid] = s;
  __syncthreads();
  s = reds[0]+reds[1]+reds[2]+reds[3];
  float inv = 1.0f / s;
  u16x8 outv;
  #pragma unroll
  for (int j=0;j<8;++j) outv[j] = f2bf(v[j]*inv);
  *(u16x8*)p = outv;
}

// ---------------- V transpose: VT[y][e][t] from Ych ----------------
__global__ __launch_bounds__(256) void k_transpose_v(const unsigned short* __restrict__ Ych,
                                                     unsigned short* __restrict__ VT){
  __shared__ unsigned short tile[64][72];
  int y = blockIdx.y; int bl = y >> 1, d = y & 1;
  int tt = (blockIdx.x & 31) * 64;     // token tile
  int te = (blockIdx.x >> 5) * 64;     // emb tile
  const unsigned short* src = Ych + (size_t)bl*SEQ*6144 + 4096 + d*1024;
  int tid = threadIdx.x;
  #pragma unroll
  for (int it=0; it<2; ++it){
    int c = it*256 + tid;
    int r = c >> 3, c8 = (c & 7) * 8;
    u16x8 v = *(const u16x8*)&src[(size_t)(tt + r)*6144 + te + c8];
    *(u16x8*)&tile[r][c8] = v;
  }
  __syncthreads();
  #pragma unroll
  for (int it=0; it<2; ++it){
    int c = it*256 + tid;
    int re = c >> 3, c8 = (c & 7) * 8;
    u16x8 o;
    #pragma unroll
    for (int j=0;j<8;++j) o[j] = tile[c8 + j][re];
    *(u16x8*)&VT[((size_t)y*EMB + te + re)*SEQ + tt + c8] = o;
  }
}

// ---------------- launch ----------------
extern "C" void kernel_launch(void* const* d_in, const int* in_sizes, int n_in,
                              void* d_out, int out_size, void* d_ws, size_t ws_size,
                              hipStream_t stream){
  const float* x  = (const float*)d_in[0];
  const float* tf = (const float*)d_in[1];
  const float* W[6]; const float* bz[6];
  for (int i=0;i<6;++i){ W[i]=(const float*)d_in[2+2*i]; bz[i]=(const float*)d_in[3+2*i]; }
  const float* Wo = (const float*)d_in[14];
  const float* bo = (const float*)d_in[15];
  float* outp = (float*)d_out;

  const size_t SZ_XB   = (size_t)8192*1024*2;     // 16 MiB
  const size_t SZ_WCAT = (size_t)12288*1024*2;    // 24 MiB
  const size_t SZ_WOB  = (size_t)1024*2048*2;     //  4 MiB
  const size_t SZ_BCAT = (size_t)12288*4;
  auto al = [](size_t b){ return (b + 255) & ~(size_t)255; };
  const size_t fixedB = al(SZ_XB) + al(SZ_WCAT) + al(SZ_WOB) + al(SZ_BCAT);

  // per-chunk (CB batch elements, one direction)
  auto chunkB = [&](int CB)->size_t {
    return al((size_t)CB*SEQ*6144*2)        // Ych
         + al((size_t)CB*2*SEQ*SEQ*2)       // Sc
         + al((size_t)CB*2*EMB*SEQ*2)       // VT
         + al((size_t)CB*SEQ*2048*2);       // AO
  };
  int CB = 4;
  while (CB > 1 && fixedB + chunkB(CB) > ws_size) CB >>= 1;
  if (fixedB + chunkB(CB) > ws_size) return;   // < ~100 MiB ws: cannot run

  char* ws = (char*)d_ws; size_t off = 0;
  auto take = [&](size_t bytes)->char* { char* p = ws + off; off += al(bytes); return p; };
  unsigned short* xb   = (unsigned short*)take(SZ_XB);
  unsigned short* Wcat = (unsigned short*)take(SZ_WCAT);
  unsigned short* WoB  = (unsigned short*)take(SZ_WOB);
  float*          bcat = (float*)take(SZ_BCAT);
  unsigned short* Ych  = (unsigned short*)take((size_t)CB*SEQ*6144*2);
  unsigned short* Sc   = (unsigned short*)take((size_t)CB*2*SEQ*SEQ*2);
  unsigned short* VT   = (unsigned short*)take((size_t)CB*2*EMB*SEQ*2);
  unsigned short* AO   = (unsigned short*)take((size_t)CB*SEQ*2048*2);

  k_cvt_bf16   <<<8192, 256, 0, stream>>>(x, xb, 2097152);
  k_build_wcat <<<12288,256, 0, stream>>>(W[0],W[1],W[2],W[3],W[4],W[5], Wcat);
  k_cvt_bf16   <<<2048, 256, 0, stream>>>(Wo, WoB, 524288);
  k_build_bcat <<<48,   256, 0, stream>>>(bz[0],bz[1],bz[2],bz[3],bz[4],bz[5], bcat);

  for (int dir = 0; dir < 2; ++dir) {
    for (int b0 = 0; b0 < 4; b0 += CB) {
      const unsigned short* xchunk = xb + (size_t)b0*SEQ*1024;
      // Ych = x_chunk @ Wdir^T + bias   ([CB*2048, 6144], K=1024)
      gemm_bt<M_LIN>  <<<dim3(CB*16*48, 1), 256, 0, stream>>>(
          xchunk, Wcat + (size_t)dir*6144*1024, nullptr, Ych,
          bcat + dir*6144, nullptr, 48, 0);
      // scores = (Q K^T) * (1/32) * tfidf[t]   per head (2*CB heads)
      gemm_bt<M_SCORE><<<dim3(16*16, 2*CB), 256, 0, stream>>>(
          Ych, nullptr, nullptr, Sc, nullptr, tf + (size_t)b0*SEQ, 16, 0);
      // softmax rows
      k_softmax    <<<2*CB*SEQ, 256, 0, stream>>>(Sc);
      // V^T per head
      k_transpose_v<<<dim3(512, 2*CB), 256, 0, stream>>>(Ych, VT);
      // AO = P V   per head
      gemm_bt<M_PV>   <<<dim3(16*8, 2*CB), 256, 0, stream>>>(
          Sc, VT, nullptr, AO, nullptr, nullptr, 8, 0);
      // out(+)= AO @ Wo^T (+ bo on dir0)
      gemm_bt<M_OUT>  <<<dim3(CB*16*8, 1), 256, 0, stream>>>(
          AO, WoB, outp + (size_t)b0*SEQ*1024, nullptr, bo, nullptr, 8, dir);
    }
  }
}

// Round 4
// 938.217 us; speedup vs baseline: 1.0844x; 1.0844x over previous
//
#include <hip/hip_runtime.h>
#include <hip/hip_bf16.h>
#include <stdint.h>

#define SEQ 2048
#define EMB 1024

typedef __attribute__((ext_vector_type(4))) float f32x4;
typedef __attribute__((ext_vector_type(8))) __bf16 bf16x8v;
typedef __attribute__((ext_vector_type(8))) unsigned short u16x8;
typedef __attribute__((ext_vector_type(4))) unsigned short u16x4;

static __device__ __forceinline__ float bf2f(unsigned short u){
  union { unsigned int i; float f; } v; v.i = ((unsigned int)u) << 16; return v.f;
}
static __device__ __forceinline__ unsigned short f2bf(float f){
  union { float f; unsigned int i; } v; v.f = f;
  unsigned int r = v.i + 0x7FFFu + ((v.i >> 16) & 1u);
  return (unsigned short)(r >> 16);
}

static __device__ __forceinline__ void gload16(const unsigned short* g, unsigned short* l){
  __builtin_amdgcn_global_load_lds(
      (__attribute__((address_space(1))) unsigned int*)(g),
      (__attribute__((address_space(3))) unsigned int*)(l), 16, 0, 0);
}

// ---------------- converters ----------------
__global__ __launch_bounds__(256) void k_cvt_bf16(const float* __restrict__ in,
                                                  unsigned short* __restrict__ out, long n4){
  long i = (long)blockIdx.x * 256 + threadIdx.x;
  if (i >= n4) return;
  float4 v = ((const float4*)in)[i];
  u16x4 o; o.x = f2bf(v.x); o.y = f2bf(v.y); o.z = f2bf(v.z); o.w = f2bf(v.w);
  ((u16x4*)out)[i] = o;
}

__global__ __launch_bounds__(256) void k_build_wcat(
    const float* __restrict__ w0, const float* __restrict__ w1,
    const float* __restrict__ w2, const float* __restrict__ w3,
    const float* __restrict__ w4, const float* __restrict__ w5,
    unsigned short* __restrict__ wcat){
  long i = (long)blockIdx.x * 256 + threadIdx.x;
  long g = i * 4;
  int m = (int)(g >> 21);
  const float* src = (m==0)?w0:(m==1)?w1:(m==2)?w2:(m==3)?w3:(m==4)?w4:w5;
  long loc = g & ((1L<<21)-1);
  float4 v = *(const float4*)&src[loc];
  u16x4 o; o.x=f2bf(v.x); o.y=f2bf(v.y); o.z=f2bf(v.z); o.w=f2bf(v.w);
  *(u16x4*)&wcat[g] = o;
}

__global__ __launch_bounds__(256) void k_build_bcat(
    const float* b0, const float* b1, const float* b2,
    const float* b3, const float* b4, const float* b5, float* __restrict__ bcat){
  int i = blockIdx.x * 256 + threadIdx.x;
  int m = i >> 11;
  const float* src = (m==0)?b0:(m==1)?b1:(m==2)?b2:(m==3)?b3:(m==4)?b4:b5;
  bcat[i] = src[i & 2047];
}

#define M_LIN   0
#define M_SCORE 1
#define M_PV    2
#define M_OUT   3

// ============ 8-phase 256xBN GEMM (C = A @ B^T), 512 threads, 8 waves ============
// T2 swizzle: 16B-slot ^= row&7 (involution, applied to ds_read addr AND gload src)
// T3/T4: 4 phases per K-tile (BK=64), counted vmcnt (never 0 in main loop), T5 setprio.
// Last K-tile is PEELED with exact drain counts (vmcnt(2)/vmcnt(0)) — the in-loop
// counted waits are no-ops when no new loads are issued (round-3 race).
template<int MODE, int BN>
__global__ __launch_bounds__(512, 2)
void gemm8(const unsigned short* __restrict__ A_,
           const unsigned short* __restrict__ B_,
           unsigned short* __restrict__ Cb,
           const float* __restrict__ bias,
           const float* __restrict__ tfb,
           int tilesN)
{
  constexpr int LDA = (MODE==M_LIN)?1024:(MODE==M_SCORE)?6144:2048;  // == LDB
  constexpr int KD  = (MODE==M_PV)?2048:1024;
  constexpr int NT  = KD/64;
  constexpr int LDC = (MODE==M_LIN)?6144:2048;
  constexpr int NREP= BN/64;     // 4 (BN=256) or 2 (BN=128)
  constexpr int NH  = NREP/2;    // frags per B-half
  constexpr int LB  = BN/128;    // gloads per B-half
  constexpr int BH  = BN/2;      // rows per B-half

  __shared__ __attribute__((aligned(16))) unsigned short As[2][2][128*64];
  __shared__ __attribute__((aligned(16))) unsigned short Bs[2][2][BH*64];

  const int tid = threadIdx.x;
  const int lane = tid & 63, wid = tid >> 6;
  const int wr = wid >> 2, wc = wid & 3;
  const int tm = blockIdx.x / tilesN, tn = blockIdx.x % tilesN;
  const int y  = blockIdx.y;

  const unsigned short *A0 = A_, *B0 = B_;
  unsigned short* Cbp = Cb;
  const float* trow = nullptr;

  if constexpr (MODE==M_SCORE) {
    const int blk = y >> 1, d = y & 1;
    A0 = A_ + (size_t)blk*SEQ*6144 + d*1024;
    B0 = A0 + 2048;
    Cbp = Cb + (size_t)y*SEQ*SEQ;
    trow = tfb + (size_t)blk*SEQ;
  } else if constexpr (MODE==M_PV) {
    A0 = A_ + (size_t)y*SEQ*SEQ;
    B0 = B_ + (size_t)y*EMB*SEQ;
    Cbp = Cb + (size_t)(y>>1)*SEQ*2048 + (y&1)*1024;
  }

  const int sr = tid >> 3, ss = tid & 7;
  const long tmrow = (long)tm*256, tncol = (long)tn*BN;
  const int lrow = lane & 15, lks = lane >> 4;

  f32x4 acc[8][NREP];
  #pragma unroll
  for (int m=0;m<8;++m)
    #pragma unroll
    for (int n=0;n<NREP;++n)
      #pragma unroll
      for (int r=0;r<4;++r) acc[m][n][r] = 0.f;

  bf16x8v am[8];            // current A-half frags: [m(0..3)*2 + kk]
  bf16x8v bl_[2*NH], bh_[2*NH];

#define STAGE_A(bufv, h, tt) { \
    const unsigned short* g_ = A0 + (size_t)(tmrow + (h)*128)*LDA + (tt)*64; \
    _Pragma("unroll") \
    for (int is=0; is<2; ++is){ \
      int r_ = is*64 + sr; \
      gload16(g_ + (size_t)r_*LDA + ((ss ^ (r_&7))*8), \
              &As[bufv][h][is*4096 + tid*8]); \
    } }

#define STAGE_B(bufv, h, tt) { \
    const unsigned short* g_ = B0 + (size_t)(tncol + (h)*BH)*LDA + (tt)*64; \
    _Pragma("unroll") \
    for (int is=0; is<LB; ++is){ \
      int r_ = is*64 + sr; \
      gload16(g_ + (size_t)r_*LDA + ((ss ^ (r_&7))*8), \
              &Bs[bufv][h][is*4096 + tid*8]); \
    } }

#define LD_A(bufv, mh) { \
    _Pragma("unroll") \
    for (int m=0;m<4;++m){ \
      int row_ = m*32 + wr*16 + lrow; \
      _Pragma("unroll") \
      for (int kk=0;kk<2;++kk){ \
        int slot_ = (kk*4 + lks) ^ (row_ & 7); \
        am[m*2+kk] = *(const bf16x8v*)&As[bufv][mh][row_*64 + slot_*8]; \
      } } }

#define LD_B(dst, bufv, nh) { \
    _Pragma("unroll") \
    for (int n=0;n<NH;++n){ \
      int row_ = n*64 + wc*16 + lrow; \
      _Pragma("unroll") \
      for (int kk=0;kk<2;++kk){ \
        int slot_ = (kk*4 + lks) ^ (row_ & 7); \
        dst[n*2+kk] = *(const bf16x8v*)&Bs[bufv][nh][row_*64 + slot_*8]; \
      } } }

#define MMAC(mh, bfrag, nh) { \
    __builtin_amdgcn_s_setprio(1); \
    _Pragma("unroll") \
    for (int m=0;m<4;++m) \
      _Pragma("unroll") \
      for (int n=0;n<NH;++n) \
        _Pragma("unroll") \
        for (int kk=0;kk<2;++kk) \
          acc[(mh)*4+m][(nh)*NH+n] = __builtin_amdgcn_mfma_f32_16x16x32_bf16( \
              am[m*2+kk], bfrag[n*2+kk], acc[(mh)*4+m][(nh)*NH+n], 0,0,0); \
    __builtin_amdgcn_s_setprio(0); \
    }

#define BARS() { __builtin_amdgcn_s_barrier(); __builtin_amdgcn_sched_barrier(0); }
#define LGK0() { asm volatile("s_waitcnt lgkmcnt(0)" ::: "memory"); __builtin_amdgcn_sched_barrier(0); }
#define VMW4() { asm volatile("s_waitcnt vmcnt(4)" ::: "memory"); }
#define VMWL() { if constexpr (LB==2) { asm volatile("s_waitcnt vmcnt(4)" ::: "memory"); } \
                 else                { asm volatile("s_waitcnt vmcnt(3)" ::: "memory"); } }

  // prologue: stage tile 0 in steady-state order A0,B0,B1,A1
  STAGE_A(0,0,0); STAGE_B(0,0,0); STAGE_B(0,1,0); STAGE_A(0,1,0);
  VMWL();          // A0(0),B0(0) landed; B1,A1 still in flight
  BARS();

  for (int t=0; t<NT-1; ++t) {
    const int buf = t & 1, nbuf = buf ^ 1;
    // ---- phase 0: quadrant (m0-3) x (n-lo) ----
    LD_A(buf, 0);
    LD_B(bl_, buf, 0);
    STAGE_A(nbuf, 0, t+1);
    VMW4();                       // gate B1(t) for phase 1
    BARS(); LGK0();
    MMAC(0, bl_, 0);
    BARS();
    // ---- phase 1: (m0-3) x (n-hi) ----
    LD_B(bh_, buf, 1);
    STAGE_B(nbuf, 0, t+1);
    VMWL();                       // gate A1(t) for phase 2
    BARS(); LGK0();
    MMAC(0, bh_, 1);
    BARS();
    // ---- phase 2: (m4-7) x (n-hi) ----
    LD_A(buf, 1);
    STAGE_B(nbuf, 1, t+1);
    BARS(); LGK0();
    MMAC(1, bh_, 1);
    BARS();
    // ---- phase 3: (m4-7) x (n-lo) ----
    STAGE_A(nbuf, 1, t+1);
    VMWL();                       // gate A0(t+1),B0(t+1) for next phase 0
    BARS(); LGK0();
    MMAC(1, bl_, 0);
    BARS();
  }

  { // ---- peeled last tile: exact drains (no new loads issued) ----
    const int buf = (NT-1) & 1;
    LD_A(buf, 0);
    LD_B(bl_, buf, 0);
    asm volatile("s_waitcnt vmcnt(2)" ::: "memory");  // drain B1(last)
    BARS(); LGK0();
    MMAC(0, bl_, 0);
    BARS();
    LD_B(bh_, buf, 1);
    asm volatile("s_waitcnt vmcnt(0)" ::: "memory");  // drain A1(last)
    BARS(); LGK0();
    MMAC(0, bh_, 1);
    BARS();                        // after this, all staging landed everywhere
    LD_A(buf, 1);
    LGK0();
    MMAC(1, bh_, 1);
    MMAC(1, bl_, 0);
  }

  // epilogue: C/D layout col = lane&15, row = (lane>>4)*4 + reg
  const int rr = (lane >> 4) * 4, cc = lane & 15;
  #pragma unroll
  for (int n=0;n<NREP;++n) {
    const long col = tncol + n*64 + wc*16 + cc;
    float cmul = 1.f, cadd = 0.f;
    if constexpr (MODE==M_SCORE) cmul = 0.03125f * trow[col];
    if constexpr (MODE==M_LIN)   cadd = bias[col];
    #pragma unroll
    for (int m=0;m<8;++m) {
      const long row = tmrow + m*32 + wr*16 + rr;
      #pragma unroll
      for (int r=0;r<4;++r) {
        float v = acc[m][n][r];
        if constexpr (MODE==M_SCORE) v *= cmul;
        if constexpr (MODE==M_LIN)   v += cadd;
        Cbp[(row + r)*LDC + col] = f2bf(v);
      }
    }
  }
#undef STAGE_A
#undef STAGE_B
#undef LD_A
#undef LD_B
#undef MMAC
#undef BARS
#undef LGK0
#undef VMW4
#undef VMWL
}

// ---------------- m97-style 128x128 GEMM, kept for OUT (f32 accumulate) ----------------
template<int MODE>
__global__ __launch_bounds__(256)
void gemm_bt(const unsigned short* __restrict__ A_,
             const unsigned short* __restrict__ B_,
             float* __restrict__ Cf, unsigned short* __restrict__ Cb,
             const float* __restrict__ bias, const float* __restrict__ tfb,
             int tilesN, int accflag)
{
  constexpr int LDA = 2048;
  constexpr int KD  = 2048;
  constexpr int LDC = 1024;

  __shared__ unsigned short As[128*64];
  __shared__ unsigned short Bs[128*64];

  const int tid  = threadIdx.x;
  const int tile = blockIdx.x;
  const int tm = tile / tilesN, tn = tile % tilesN;

  const unsigned short *A0 = A_, *B0 = B_;
  float* Cfp = Cf;

  const int rbase = tid >> 3, cel = (tid & 7) * 8;
  const int wid = tid >> 6, lane = tid & 63;
  const int wr = wid >> 1, wc = wid & 1;
  const int lrow = lane & 15, lk = (lane >> 4) * 8;

  f32x4 acc[4][4];
  #pragma unroll
  for (int m=0;m<4;++m)
    #pragma unroll
    for (int n=0;n<4;++n)
      #pragma unroll
      for (int r=0;r<4;++r) acc[m][n][r] = 0.f;

  const unsigned short* gA = A0 + (size_t)(tm*128 + rbase)*LDA + cel;
  const unsigned short* gB = B0 + (size_t)(tn*128 + rbase)*LDA + cel;
  for (int k0 = 0; k0 < KD; k0 += 64) {
    #pragma unroll
    for (int it = 0; it < 4; ++it) {
      gload16(gA + (size_t)(it*32)*LDA + k0, &As[it*2048 + tid*8]);
      gload16(gB + (size_t)(it*32)*LDA + k0, &Bs[it*2048 + tid*8]);
    }
    __syncthreads();
    #pragma unroll
    for (int kk = 0; kk < 2; ++kk) {
      bf16x8v a[4], b[4];
      #pragma unroll
      for (int m=0;m<4;++m) a[m] = *(const bf16x8v*)&As[(wr*64+m*16+lrow)*64 + kk*32 + lk];
      #pragma unroll
      for (int n=0;n<4;++n) b[n] = *(const bf16x8v*)&Bs[(wc*64+n*16+lrow)*64 + kk*32 + lk];
      #pragma unroll
      for (int m=0;m<4;++m)
        #pragma unroll
        for (int n=0;n<4;++n)
          acc[m][n] = __builtin_amdgcn_mfma_f32_16x16x32_bf16(a[m], b[n], acc[m][n], 0, 0, 0);
    }
    __syncthreads();
  }

  const int rr = (lane >> 4) * 4, cc = lane & 15;
  const int row0 = tm*128 + wr*64, col0 = tn*128 + wc*64;
  #pragma unroll
  for (int n=0;n<4;++n) {
    int col = col0 + n*16 + cc;
    #pragma unroll
    for (int m=0;m<4;++m) {
      #pragma unroll
      for (int r=0;r<4;++r) {
        int row = row0 + m*16 + rr + r;
        size_t idx = (size_t)row*LDC + col;
        float v = acc[m][n][r];
        float w = v + (accflag ? Cfp[idx] : bias[col]);
        Cfp[idx] = w;
      }
    }
  }
}

// ---------------- row softmax (in-place, bf16) ----------------
__global__ __launch_bounds__(256) void k_softmax(unsigned short* __restrict__ Sc){
  long row = blockIdx.x;
  unsigned short* p = Sc + row*SEQ + threadIdx.x*8;
  u16x8 raw = *(const u16x8*)p;
  float v[8]; float mx = -3.0e38f;
  #pragma unroll
  for (int j=0;j<8;++j){ v[j] = bf2f(raw[j]); mx = fmaxf(mx, v[j]); }
  #pragma unroll
  for (int o=1;o<64;o<<=1) mx = fmaxf(mx, __shfl_xor(mx, o));
  __shared__ float redm[4], reds[4];
  int wid = threadIdx.x >> 6, lane = threadIdx.x & 63;
  if (lane == 0) redm[wid] = mx;
  __syncthreads();
  mx = fmaxf(fmaxf(redm[0],redm[1]), fmaxf(redm[2],redm[3]));
  float s = 0.f;
  #pragma unroll
  for (int j=0;j<8;++j){ v[j] = __expf(v[j]-mx); s += v[j]; }
  #pragma unroll
  for (int o=1;o<64;o<<=1) s += __shfl_xor(s, o);
  if (lane == 0) reds[wid] = s;
  __syncthreads();
  s = reds[0]+reds[1]+reds[2]+reds[3];
  float inv = 1.0f / s;
  u16x8 outv;
  #pragma unroll
  for (int j=0;j<8;++j) outv[j] = f2bf(v[j]*inv);
  *(u16x8*)p = outv;
}

// ---------------- V transpose: VT[y][e][t] from Ych ----------------
__global__ __launch_bounds__(256) void k_transpose_v(const unsigned short* __restrict__ Ych,
                                                     unsigned short* __restrict__ VT){
  __shared__ unsigned short tile[64][72];
  int y = blockIdx.y; int blk = y >> 1, d = y & 1;
  int tt = (blockIdx.x & 31) * 64;
  int te = (blockIdx.x >> 5) * 64;
  const unsigned short* src = Ych + (size_t)blk*SEQ*6144 + 4096 + d*1024;
  int tid = threadIdx.x;
  #pragma unroll
  for (int it=0; it<2; ++it){
    int c = it*256 + tid;
    int r = c >> 3, c8 = (c & 7) * 8;
    u16x8 v = *(const u16x8*)&src[(size_t)(tt + r)*6144 + te + c8];
    *(u16x8*)&tile[r][c8] = v;
  }
  __syncthreads();
  #pragma unroll
  for (int it=0; it<2; ++it){
    int c = it*256 + tid;
    int re = c >> 3, c8 = (c & 7) * 8;
    u16x8 o;
    #pragma unroll
    for (int j=0;j<8;++j) o[j] = tile[c8 + j][re];
    *(u16x8*)&VT[((size_t)y*EMB + te + re)*SEQ + tt + c8] = o;
  }
}

// ---------------- launch ----------------
extern "C" void kernel_launch(void* const* d_in, const int* in_sizes, int n_in,
                              void* d_out, int out_size, void* d_ws, size_t ws_size,
                              hipStream_t stream){
  const float* x  = (const float*)d_in[0];
  const float* tf = (const float*)d_in[1];
  const float* W[6]; const float* bz[6];
  for (int i=0;i<6;++i){ W[i]=(const float*)d_in[2+2*i]; bz[i]=(const float*)d_in[3+2*i]; }
  const float* Wo = (const float*)d_in[14];
  const float* bo = (const float*)d_in[15];
  float* outp = (float*)d_out;

  const size_t SZ_XB   = (size_t)8192*1024*2;
  const size_t SZ_WCAT = (size_t)12288*1024*2;
  const size_t SZ_WOB  = (size_t)1024*2048*2;
  const size_t SZ_BCAT = (size_t)12288*4;
  auto al = [](size_t b){ return (b + 255) & ~(size_t)255; };
  const size_t fixedB = al(SZ_XB) + al(SZ_WCAT) + al(SZ_WOB) + al(SZ_BCAT);

  auto chunkB = [&](int CB)->size_t {
    return al((size_t)CB*SEQ*6144*2)
         + al((size_t)CB*2*SEQ*SEQ*2)
         + al((size_t)CB*2*EMB*SEQ*2)
         + al((size_t)CB*SEQ*2048*2);
  };
  int CB = 4;
  while (CB > 1 && fixedB + chunkB(CB) > ws_size) CB >>= 1;
  if (fixedB + chunkB(CB) > ws_size) return;

  char* ws = (char*)d_ws; size_t off = 0;
  auto take = [&](size_t bytes)->char* { char* p = ws + off; off += al(bytes); return p; };
  unsigned short* xb   = (unsigned short*)take(SZ_XB);
  unsigned short* Wcat = (unsigned short*)take(SZ_WCAT);
  unsigned short* WoB  = (unsigned short*)take(SZ_WOB);
  float*          bcat = (float*)take(SZ_BCAT);
  unsigned short* Ych  = (unsigned short*)take((size_t)CB*SEQ*6144*2);
  unsigned short* Sc   = (unsigned short*)take((size_t)CB*2*SEQ*SEQ*2);
  unsigned short* VT   = (unsigned short*)take((size_t)CB*2*EMB*SEQ*2);
  unsigned short* AO   = (unsigned short*)take((size_t)CB*SEQ*2048*2);

  k_cvt_bf16   <<<8192, 256, 0, stream>>>(x, xb, 2097152);
  k_build_wcat <<<12288,256, 0, stream>>>(W[0],W[1],W[2],W[3],W[4],W[5], Wcat);
  k_cvt_bf16   <<<2048, 256, 0, stream>>>(Wo, WoB, 524288);
  k_build_bcat <<<48,   256, 0, stream>>>(bz[0],bz[1],bz[2],bz[3],bz[4],bz[5], bcat);

  for (int dir = 0; dir < 2; ++dir) {
    for (int b0 = 0; b0 < 4; b0 += CB) {
      const unsigned short* xchunk = xb + (size_t)b0*SEQ*1024;
      // Ych = x_chunk @ Wdir^T + bias   ([CB*2048, 6144], K=1024)
      gemm8<M_LIN,256><<<dim3(CB*8*24, 1), 512, 0, stream>>>(
          xchunk, Wcat + (size_t)dir*6144*1024, Ych,
          bcat + dir*6144, nullptr, 24);
      // scores = (Q K^T) * (1/32) * tfidf[t]   per head (2*CB heads)
      gemm8<M_SCORE,256><<<dim3(64, 2*CB), 512, 0, stream>>>(
          Ych, nullptr, Sc, nullptr, tf + (size_t)b0*SEQ, 8);
      // softmax rows
      k_softmax    <<<2*CB*SEQ, 256, 0, stream>>>(Sc);
      // V^T per head
      k_transpose_v<<<dim3(512, 2*CB), 256, 0, stream>>>(Ych, VT);
      // AO = P V   per head (BN=128 -> 64 tiles x 2CB heads)
      gemm8<M_PV,128><<<dim3(64, 2*CB), 512, 0, stream>>>(
          Sc, VT, AO, nullptr, nullptr, 8);
      // out(+)= AO @ Wo^T (+ bo on dir0)
      gemm_bt<M_OUT>  <<<dim3(CB*16*8, 1), 256, 0, stream>>>(
          AO, WoB, outp + (size_t)b0*SEQ*1024, nullptr, bo, nullptr, 8, dir);
    }
  }
}

// Round 5
// 764.590 us; speedup vs baseline: 1.3306x; 1.2271x over previous
//
#include <hip/hip_runtime.h>
#include <hip/hip_bf16.h>
#include <stdint.h>

#define SEQ 2048
#define EMB 1024

typedef __attribute__((ext_vector_type(4))) float f32x4;
typedef __attribute__((ext_vector_type(8))) __bf16 bf16x8v;
typedef __attribute__((ext_vector_type(8))) unsigned short u16x8;
typedef __attribute__((ext_vector_type(4))) unsigned short u16x4;

static __device__ __forceinline__ float bf2f(unsigned short u){
  union { unsigned int i; float f; } v; v.i = ((unsigned int)u) << 16; return v.f;
}
static __device__ __forceinline__ unsigned short f2bf(float f){
  union { float f; unsigned int i; } v; v.f = f;
  unsigned int r = v.i + 0x7FFFu + ((v.i >> 16) & 1u);
  return (unsigned short)(r >> 16);
}

static __device__ __forceinline__ void gload16(const unsigned short* g, unsigned short* l){
  __builtin_amdgcn_global_load_lds(
      (__attribute__((address_space(1))) unsigned int*)(g),
      (__attribute__((address_space(3))) unsigned int*)(l), 16, 0, 0);
}

// XCD-aware tile swizzle (valid when nwg % 8 == 0): XCD k gets contiguous tiles.
static __device__ __forceinline__ int xcd_swz(int bid, int nwg){
  int q = nwg >> 3;
  return (bid & 7) * q + (bid >> 3);
}

// ---------------- converters ----------------
__global__ __launch_bounds__(256) void k_cvt_bf16(const float* __restrict__ in,
                                                  unsigned short* __restrict__ out, long n4){
  long i = (long)blockIdx.x * 256 + threadIdx.x;
  if (i >= n4) return;
  float4 v = ((const float4*)in)[i];
  u16x4 o; o.x = f2bf(v.x); o.y = f2bf(v.y); o.z = f2bf(v.z); o.w = f2bf(v.w);
  ((u16x4*)out)[i] = o;
}

__global__ __launch_bounds__(256) void k_build_wcat(
    const float* __restrict__ w0, const float* __restrict__ w1,
    const float* __restrict__ w2, const float* __restrict__ w3,
    const float* __restrict__ w4, const float* __restrict__ w5,
    unsigned short* __restrict__ wcat){
  long i = (long)blockIdx.x * 256 + threadIdx.x;
  long g = i * 4;
  int m = (int)(g >> 21);
  const float* src = (m==0)?w0:(m==1)?w1:(m==2)?w2:(m==3)?w3:(m==4)?w4:w5;
  long loc = g & ((1L<<21)-1);
  float4 v = *(const float4*)&src[loc];
  u16x4 o; o.x=f2bf(v.x); o.y=f2bf(v.y); o.z=f2bf(v.z); o.w=f2bf(v.w);
  *(u16x4*)&wcat[g] = o;
}

__global__ __launch_bounds__(256) void k_build_bcat(
    const float* b0, const float* b1, const float* b2,
    const float* b3, const float* b4, const float* b5, float* __restrict__ bcat){
  int i = blockIdx.x * 256 + threadIdx.x;
  int m = i >> 11;
  const float* src = (m==0)?b0:(m==1)?b1:(m==2)?b2:(m==3)?b3:(m==4)?b4:b5;
  bcat[i] = src[i & 2047];
}

#define M_LIN   0
#define M_SCORE 1
#define M_PV    2
#define M_OUT   3

// ============ 256xBN GEMM (C = A @ B^T), 512 threads, 8 waves (2x4) ============
// Full-tile LDS double-buffer, ONE __syncthreads per K-tile (BK=64).
// T2 swizzle: 16B slot ^= row&7 on both gload source and ds_read (involution).
// Stage for tile t+1 issued at top of tile t -> full tile to cover latency;
// __syncthreads' vmcnt(0)+lgkmcnt(0) drain makes the handoff airtight.
template<int MODE, int BN>
__global__ __launch_bounds__(512, 2)
void gemm8(const unsigned short* __restrict__ A_,
           const unsigned short* __restrict__ B_,
           unsigned short* __restrict__ Cb, float* __restrict__ Cf,
           const float* __restrict__ bias, const float* __restrict__ tfb,
           int ld, int ldc, int tilesN, int accflag)
{
  constexpr int KD  = (MODE==M_PV || MODE==M_OUT) ? 2048 : 1024;
  constexpr int NT  = KD/64;
  constexpr int NREP= BN/64;      // 4 (BN=256) or 2 (BN=128)
  constexpr int NLO = NREP/2;     // 2 or 1
  constexpr int GB  = BN/64;      // B stage passes

  __shared__ __attribute__((aligned(16))) unsigned short As[2][256*64];
  __shared__ __attribute__((aligned(16))) unsigned short Bs[2][BN*64];

  const int tid = threadIdx.x;
  const int lane = tid & 63, wid = tid >> 6;
  const int wr = wid >> 2, wc = wid & 3;

  const int tile = xcd_swz(blockIdx.x, gridDim.x);
  const int tm = tile / tilesN, tn = tile % tilesN;
  const int y  = blockIdx.y;

  const unsigned short *A0 = A_, *B0 = B_;
  unsigned short* Cbp = Cb;
  float* Cfp = Cf;
  const float* trow = nullptr;

  if constexpr (MODE==M_SCORE) {
    const int bl = y >> 1, d = y & 1;
    A0 = A_ + (size_t)bl*SEQ*ld + d*1024;
    B0 = A0 + 2048;
    Cbp = Cb + (size_t)y*SEQ*SEQ;
    trow = tfb + (size_t)bl*SEQ;
  } else if constexpr (MODE==M_PV) {
    A0 = A_ + (size_t)y*SEQ*SEQ;
    B0 = B_ + (size_t)y*EMB*SEQ;
    Cbp = Cb + (size_t)(y>>1)*SEQ*2048 + (y&1)*1024;
  }

  const int sr = tid >> 3, ss = tid & 7;
  const int swz = (ss ^ (sr & 7)) * 8;       // pre-swizzled global col offset
  const long tmrow = (long)tm*256, tncol = (long)tn*BN;
  const int lrow = lane & 15, lks = lane >> 4;

  const unsigned short* gA = A0 + (size_t)(tmrow + sr)*ld + swz;
  const unsigned short* gB = B0 + (size_t)(tncol + sr)*ld + swz;

  f32x4 acc[8][NREP];
  #pragma unroll
  for (int m=0;m<8;++m)
    #pragma unroll
    for (int n=0;n<NREP;++n)
      #pragma unroll
      for (int r=0;r<4;++r) acc[m][n][r] = 0.f;

#define STAGE(nb_, t_) { \
    const long ko_ = (long)(t_)*64; \
    _Pragma("unroll") \
    for (int p=0;p<4;++p) \
      gload16(gA + (size_t)(p*64)*ld + ko_, &As[nb_][p*4096 + tid*8]); \
    _Pragma("unroll") \
    for (int p=0;p<GB;++p) \
      gload16(gB + (size_t)(p*64)*ld + ko_, &Bs[nb_][p*4096 + tid*8]); }

#define LDA_F(dst, mh) { \
    _Pragma("unroll") \
    for (int m=0;m<4;++m){ \
      int row_ = (m + 4*(mh))*32 + wr*16 + lrow; \
      _Pragma("unroll") \
      for (int kk=0;kk<2;++kk){ \
        int slot_ = (kk*4 + lks) ^ (row_ & 7); \
        dst[m*2+kk] = *(const bf16x8v*)&As[buf][row_*64 + slot_*8]; \
      } } }

#define LDB_F(dst, nh) { \
    _Pragma("unroll") \
    for (int n=0;n<NLO;++n){ \
      int row_ = (n + NLO*(nh))*64 + wc*16 + lrow; \
      _Pragma("unroll") \
      for (int kk=0;kk<2;++kk){ \
        int slot_ = (kk*4 + lks) ^ (row_ & 7); \
        dst[n*2+kk] = *(const bf16x8v*)&Bs[buf][row_*64 + slot_*8]; \
      } } }

#define MMAC(mh, bfrag, nh) { \
    __builtin_amdgcn_s_setprio(1); \
    _Pragma("unroll") \
    for (int m=0;m<4;++m) \
      _Pragma("unroll") \
      for (int n=0;n<NLO;++n) \
        _Pragma("unroll") \
        for (int kk=0;kk<2;++kk) \
          acc[(mh)*4+m][(nh)*NLO+n] = __builtin_amdgcn_mfma_f32_16x16x32_bf16( \
              aF[m*2+kk], bfrag[n*2+kk], acc[(mh)*4+m][(nh)*NLO+n], 0,0,0); \
    __builtin_amdgcn_s_setprio(0); }

#define TILE_BODY() { \
    bf16x8v aF[8], bL[2*NLO], bH[2*NLO]; \
    LDA_F(aF, 0); \
    LDB_F(bL, 0); \
    MMAC(0, bL, 0); \
    LDB_F(bH, 1); \
    MMAC(0, bH, 1); \
    LDA_F(aF, 1); \
    MMAC(1, bH, 1); \
    MMAC(1, bL, 0); }

  // prologue
  STAGE(0, 0);
  __syncthreads();

  for (int t = 0; t < NT-1; ++t) {
    const int buf = t & 1;
    STAGE(buf ^ 1, t+1);      // issue next tile's loads first; land by barrier
    TILE_BODY();
    __syncthreads();          // drains this wave's stages (vmcnt 0) + LDS handoff
  }
  { // peeled last tile (no stage)
    const int buf = (NT-1) & 1;
    TILE_BODY();
  }

  // epilogue: C/D layout col = lane&15, row = (lane>>4)*4 + reg
  const int rr = (lane >> 4) * 4, cc = lane & 15;
  #pragma unroll
  for (int n=0;n<NREP;++n) {
    const long col = tncol + n*64 + wc*16 + cc;
    float cmul = 1.f, cadd = 0.f;
    if constexpr (MODE==M_SCORE) cmul = 0.03125f * trow[col];
    if constexpr (MODE==M_LIN)   cadd = bias[col];
    if constexpr (MODE==M_OUT)   cadd = bias[col];
    #pragma unroll
    for (int m=0;m<8;++m) {
      const long row = tmrow + m*32 + wr*16 + rr;
      #pragma unroll
      for (int r=0;r<4;++r) {
        float v = acc[m][n][r];
        if constexpr (MODE==M_SCORE) v *= cmul;
        else v += cadd;
        if constexpr (MODE==M_OUT) {
          Cfp[(row + r)*ldc + col] = v;
        } else if constexpr (MODE==M_PV) {
          size_t idx = (row + r)*(size_t)ldc + col;
          float w = v + (accflag ? bf2f(Cbp[idx]) : 0.f);
          Cbp[idx] = f2bf(w);
        } else {
          Cbp[(row + r)*(size_t)ldc + col] = f2bf(v);
        }
      }
    }
  }
#undef STAGE
#undef LDA_F
#undef LDB_F
#undef MMAC
#undef TILE_BODY
}

// ---------------- row softmax (in-place, bf16) ----------------
__global__ __launch_bounds__(256) void k_softmax(unsigned short* __restrict__ Sc){
  long row = blockIdx.x;
  unsigned short* p = Sc + row*SEQ + threadIdx.x*8;
  u16x8 raw = *(const u16x8*)p;
  float v[8]; float mx = -3.0e38f;
  #pragma unroll
  for (int j=0;j<8;++j){ v[j] = bf2f(raw[j]); mx = fmaxf(mx, v[j]); }
  #pragma unroll
  for (int o=1;o<64;o<<=1) mx = fmaxf(mx, __shfl_xor(mx, o));
  __shared__ float redm[4], reds[4];
  int wid = threadIdx.x >> 6, lane = threadIdx.x & 63;
  if (lane == 0) redm[wid] = mx;
  __syncthreads();
  mx = fmaxf(fmaxf(redm[0],redm[1]), fmaxf(redm[2],redm[3]));
  float s = 0.f;
  #pragma unroll
  for (int j=0;j<8;++j){ v[j] = __expf(v[j]-mx); s += v[j]; }
  #pragma unroll
  for (int o=1;o<64;o<<=1) s += __shfl_xor(s, o);
  if (lane == 0) reds[wid] = s;
  __syncthreads();
  s = reds[0]+reds[1]+reds[2]+reds[3];
  float inv = 1.0f / s;
  u16x8 outv;
  #pragma unroll
  for (int j=0;j<8;++j) outv[j] = f2bf(v[j]*inv);
  *(u16x8*)p = outv;
}

// ---------------- V transpose: VT[y][e][t] ----------------
__global__ __launch_bounds__(256) void k_transpose_v(const unsigned short* __restrict__ Vsrc,
                                                     unsigned short* __restrict__ VT, int ld){
  __shared__ unsigned short tile[64][72];
  int y = blockIdx.y; int bl = y >> 1, d = y & 1;
  int tt = (blockIdx.x & 31) * 64;
  int te = (blockIdx.x >> 5) * 64;
  const unsigned short* src = Vsrc + (size_t)bl*SEQ*ld + d*1024;
  int tid = threadIdx.x;
  #pragma unroll
  for (int it=0; it<2; ++it){
    int c = it*256 + tid;
    int r = c >> 3, c8 = (c & 7) * 8;
    u16x8 v = *(const u16x8*)&src[(size_t)(tt + r)*ld + te + c8];
    *(u16x8*)&tile[r][c8] = v;
  }
  __syncthreads();
  #pragma unroll
  for (int it=0; it<2; ++it){
    int c = it*256 + tid;
    int re = c >> 3, c8 = (c & 7) * 8;
    u16x8 o;
    #pragma unroll
    for (int j=0;j<8;++j) o[j] = tile[c8 + j][re];
    *(u16x8*)&VT[((size_t)y*EMB + te + re)*SEQ + tt + c8] = o;
  }
}

// ---------------- launch ----------------
extern "C" void kernel_launch(void* const* d_in, const int* in_sizes, int n_in,
                              void* d_out, int out_size, void* d_ws, size_t ws_size,
                              hipStream_t stream){
  const float* x  = (const float*)d_in[0];
  const float* tf = (const float*)d_in[1];
  const float* W[6]; const float* bz[6];
  for (int i=0;i<6;++i){ W[i]=(const float*)d_in[2+2*i]; bz[i]=(const float*)d_in[3+2*i]; }
  const float* Wo = (const float*)d_in[14];
  const float* bo = (const float*)d_in[15];
  float* outp = (float*)d_out;

  auto al = [](size_t b){ return (b + 255) & ~(size_t)255; };
  const size_t SZ_XB   = (size_t)8192*1024*2;
  const size_t SZ_WCAT = (size_t)12288*1024*2;
  const size_t SZ_WOB  = (size_t)1024*2048*2;
  const size_t SZ_BCAT = (size_t)12288*4;
  const size_t SZ_AO   = (size_t)8192*2048*2;        // full, both chunks, dirs summed
  const size_t fixedB  = al(SZ_XB)+al(SZ_WCAT)+al(SZ_WOB)+al(SZ_BCAT)+al(SZ_AO);

  auto chB = [&](int CB, bool merged)->size_t {
    return al((size_t)CB*SEQ*(merged?12288:6144)*2)   // Ych
         + al((size_t)CB*2*SEQ*SEQ*2)                 // Sc (per dir)
         + al((size_t)CB*2*EMB*SEQ*2);                // VT (per dir)
  };
  int CB; bool merged;
  if      (ws_size >= fixedB + chB(2,true))  { CB=2; merged=true;  }
  else if (ws_size >= fixedB + chB(2,false)) { CB=2; merged=false; }
  else if (ws_size >= fixedB + chB(1,false)) { CB=1; merged=false; }
  else return;
  const int ldY = merged ? 12288 : 6144;

  char* ws = (char*)d_ws; size_t off = 0;
  auto take = [&](size_t bytes)->char* { char* p = ws + off; off += al(bytes); return p; };
  unsigned short* xb   = (unsigned short*)take(SZ_XB);
  unsigned short* Wcat = (unsigned short*)take(SZ_WCAT);
  unsigned short* WoB  = (unsigned short*)take(SZ_WOB);
  float*          bcat = (float*)take(SZ_BCAT);
  unsigned short* AO   = (unsigned short*)take(SZ_AO);
  unsigned short* Ych  = (unsigned short*)take((size_t)CB*SEQ*ldY*2);
  unsigned short* Sc   = (unsigned short*)take((size_t)CB*2*SEQ*SEQ*2);
  unsigned short* VT   = (unsigned short*)take((size_t)CB*2*EMB*SEQ*2);

  k_cvt_bf16   <<<8192, 256, 0, stream>>>(x, xb, 2097152);
  k_build_wcat <<<12288,256, 0, stream>>>(W[0],W[1],W[2],W[3],W[4],W[5], Wcat);
  k_cvt_bf16   <<<2048, 256, 0, stream>>>(Wo, WoB, 524288);
  k_build_bcat <<<48,   256, 0, stream>>>(bz[0],bz[1],bz[2],bz[3],bz[4],bz[5], bcat);

  for (int c = 0; c < 4/CB; ++c) {
    const int b0 = c*CB;
    const unsigned short* xchunk = xb + (size_t)b0*SEQ*1024;
    if (merged) {
      // Ych = x_chunk @ [W_f|W_b]^T + b   ([CB*2048, 12288], K=1024)
      gemm8<M_LIN,256><<<dim3(CB*8*48, 1), 512, 0, stream>>>(
          xchunk, Wcat, Ych, nullptr, bcat, nullptr, 1024, 12288, 48, 0);
    }
    for (int dir = 0; dir < 2; ++dir) {
      const unsigned short* Ybase = Ych + (merged ? dir*6144 : 0);
      if (!merged) {
        gemm8<M_LIN,256><<<dim3(CB*8*24, 1), 512, 0, stream>>>(
            xchunk, Wcat + (size_t)dir*6144*1024, Ych, nullptr,
            bcat + dir*6144, nullptr, 1024, 6144, 24, 0);
      }
      // scores = (Q K^T) * (1/32) * tfidf[t]   per head (2*CB heads)
      gemm8<M_SCORE,256><<<dim3(64, 2*CB), 512, 0, stream>>>(
          Ybase, nullptr, Sc, nullptr, nullptr, tf + (size_t)b0*SEQ,
          ldY, 2048, 8, 0);
      k_softmax    <<<2*CB*SEQ, 256, 0, stream>>>(Sc);
      k_transpose_v<<<dim3(512, 2*CB), 256, 0, stream>>>(Ybase + 4096, VT, ldY);
      // AO[chunk] (+)= P V   per head; accumulate over dir
      gemm8<M_PV,128><<<dim3(64, 2*CB), 512, 0, stream>>>(
          Sc, VT, AO + (size_t)b0*SEQ*2048, nullptr, nullptr, nullptr,
          2048, 2048, 8, dir);
    }
  }
  // out = AO @ Wo^T + bo   ([8192,1024], K=2048, f32) — one dispatch, 256 blocks
  gemm8<M_OUT,128><<<dim3(256, 1), 512, 0, stream>>>(
      AO, WoB, nullptr, outp, bo, nullptr, 2048, 1024, 8, 0);
}